// Round 14
// baseline (315.087 us; speedup 1.0000x reference)
//
#include <hip/hip_runtime.h>
#include <cstdint>
#include <cstddef>

#define Bb 128
#define Tt 2048
#define Dd 512
#define Hh 512
#define Mtot (Bb*Tt)
#define NG 1152   // scores grid; grid-stride covers pathological masks

typedef __attribute__((ext_vector_type(8))) _Float16 h8;
typedef __attribute__((ext_vector_type(4))) _Float16 h4v;
typedef __attribute__((ext_vector_type(4))) float f4;

// Direct global->LDS DMA, 16B per lane. LDS dest is WAVE-UNIFORM base; HW
// writes lane l at base + l*16. Global src is per-lane (pre-swizzled).
#define GLOAD_LDS16(gsrc, ldst) \
    __builtin_amdgcn_global_load_lds((const __attribute__((address_space(1))) void*)(gsrc), \
                                     (__attribute__((address_space(3))) void*)(ldst), 16, 0, 0)

__device__ __forceinline__ h4v cvt4s(const float4 a) {
    h4v h;
    h[0] = (_Float16)a.x; h[1] = (_Float16)a.y;
    h[2] = (_Float16)a.z; h[3] = (_Float16)a.w;
    return h;
}

// ---------------- kernel 1: fused prep ----------------
__global__ __launch_bounds__(256) void prep_kernel(
    const float* __restrict__ W, _Float16* __restrict__ W16,
    const int* __restrict__ mask, int* __restrict__ cidx, int* __restrict__ cnt,
    int* __restrict__ tlist, int* __restrict__ ntiles,
    const float* __restrict__ col, float* __restrict__ colt)
{
    const int blk = blockIdx.x, tid = threadIdx.x;
    if (blk < 1024) {                       // ---- W16 cast ----
        int i = blk * 256 + tid;
        W16[i] = (_Float16)W[i];
        return;
    }
    if (blk < 1152) {                       // ---- compaction (b = blk-1024) ----
        __shared__ int wsum[4];
        int b = blk - 1024;
        const int* mrow = mask + (size_t)b * Tt;
        int mv[8], c = 0;
#pragma unroll
        for (int i = 0; i < 8; i++) {
            mv[i] = mrow[tid * 8 + i];
            c += mv[i];
        }
        int lane = tid & 63, wv = tid >> 6;
        int inc = c;
#pragma unroll
        for (int off = 1; off < 64; off <<= 1) {
            int n = __shfl_up(inc, off);
            if (lane >= off) inc += n;
        }
        if (lane == 63) wsum[wv] = inc;
        __syncthreads();
        int wbase = 0;
        for (int w = 0; w < wv; w++) wbase += wsum[w];
        int pos = wbase + inc - c;          // exclusive prefix
        int* crow = cidx + (size_t)b * Tt;
#pragma unroll
        for (int i = 0; i < 8; i++)
            if (mv[i]) crow[pos++] = tid * 8 + i;
        if (tid == 255) {
            int total = wbase + inc;
            cnt[b] = total;
            int nt = (total + 127) >> 7;    // tiles of 128 rows
            int base = atomicAdd(ntiles, nt);
            for (int i = 0; i < nt; i++) tlist[base + i] = (b << 8) | i;
        }
        return;
    }
    {                                        // ---- col_proj ----
        __shared__ float c[Dd];
        int idx = blk - 1152;
        int b = idx >> 1;
        int h = (idx & 1) * 256 + tid;
        c[tid] = col[b * Dd + tid];
        c[tid + 256] = col[b * Dd + 256 + tid];
        __syncthreads();
        const f4* w4 = (const f4*)(W + (size_t)h * Dd);
        float acc = 0.f;
#pragma unroll 8
        for (int k = 0; k < Dd / 4; k++) {
            f4 w = w4[k];
            acc += w.x * c[4 * k] + w.y * c[4 * k + 1] + w.z * c[4 * k + 2] + w.w * c[4 * k + 3];
        }
        colt[b * Hh + h] = fmaxf(acc, 0.f);
    }
}

// ---------------- kernel 2: scores GEMM — R9 EXACT (best known: 125.5us) -----
// BM=128, BN=512, BK=32, 16 K-steps, 16 waves = 4M x 4N, wave tile 32x128,
// acc f4[2][8]. W dbuf via global_load_lds; X dbuf via regs. vmcnt(1) audit:
// per-step queue after cvt(X(t+1)) = [Wa(t+1), Wb(t+1), X(t+2)] -> vmcnt(1)
// certifies both W-DMAs, leaves the X prefetch in flight.
__global__ __launch_bounds__(1024, 4) void scores_kernel(
    const float* __restrict__ X,        // [B*T][512]
    const _Float16* __restrict__ W16,   // [512][512]
    const float* __restrict__ colt,     // [128][512]
    const int* __restrict__ cidx,       // [B][T]
    const int* __restrict__ cnt,        // [B]
    const int* __restrict__ tlist,      // work list: (b<<8)|tile
    const int* __restrict__ ntiles,     // [1]
    float* __restrict__ scores)         // [B*T] (masked entries untouched)
{
    const int tid = threadIdx.x;
    const int total = ntiles[0];

    // LDS: bufW 2x32KB @0/32768; bufX 2x8KB @65536/73728; sred[4][128] (2KB)
    // aliases bufX[0] (written only after the final barrier). Total 80KB.
    __shared__ __align__(16) char lds[81920];
    float (*sred)[128] = (float(*)[128])(lds + 65536);

    const int wave = tid >> 6;
    const int lane = tid & 63;
    const int wm = wave >> 2;   // 0..3 : M quarter (rows wm*32..+32)
    const int wn = wave & 3;    // 0..3 : N strip (cols wn*128..+128)
    const int l16 = lane & 15;
    const int khi = lane >> 4;  // 0..3

    int wsrcoff[2];
#pragma unroll
    for (int j = 0; j < 2; j++) {
        int r = (j * 16 + wave) * 16 + (lane >> 2);
        int c = (lane & 3) ^ ((r >> 1) & 3);
        wsrcoff[j] = r * Dd + c * 8;
    }
    const int wldsoff = wave * 1024;   // + j*16384 per chunk-call

    const int xrow = tid >> 3, xf4 = tid & 7;
    const int xoff = xrow * 64 + (((xf4 >> 1) ^ ((xrow >> 1) & 3)) << 4) + (xf4 & 1) * 8;

    for (int idx = blockIdx.x; idx < total; idx += NG) {
        const int ent = tlist[idx];
        const int b = ent >> 8;
        const int tile = ent & 255;
        const int count = cnt[b];
        const int r0 = tile * 128;

        const int* crow = cidx + (size_t)b * Tt;
        int rl = r0 + xrow; if (rl >= count) rl = count - 1;  // clamp (dup, never stored)
        const float* xsrc = X + ((size_t)b * Tt + crow[rl]) * Dd + xf4 * 4;

        f4 acc[2][8];
#pragma unroll
        for (int i = 0; i < 2; i++)
#pragma unroll
            for (int j = 0; j < 8; j++) {
                f4 z = {0.f, 0.f, 0.f, 0.f};
                acc[i][j] = z;
            }

        // ---- prologue: W_0 DMA -> bufW0; X_0 -> LDS; X_1 -> regs ----
        __builtin_amdgcn_sched_barrier(0);
#pragma unroll
        for (int j = 0; j < 2; j++)
            GLOAD_LDS16(W16 + wsrcoff[j], lds + wldsoff + j * 16384);
        __builtin_amdgcn_sched_barrier(0);
        float4 x0 = *(const float4*)(xsrc);
        float4 xu = *(const float4*)(xsrc + 32);
        __builtin_amdgcn_sched_barrier(0);
        {
            h4v hv = cvt4s(x0);        // waits x0 -> drains W_0 DMAs too (in-order)
            *(h4v*)(lds + 65536 + xoff) = hv;
        }
        asm volatile("s_waitcnt vmcnt(1) lgkmcnt(0)" ::: "memory");
        __builtin_amdgcn_sched_barrier(0);
        __builtin_amdgcn_s_barrier();
        __builtin_amdgcn_sched_barrier(0);

#pragma unroll 2
        for (int t = 0; t < 16; ++t) {
            const int cur = t & 1;
            const int kW = (t < 15 ? t + 1 : 15) * 32;  // halfs (tail: dead re-stage)
            const int kX = (t < 14 ? t + 2 : 15) * 32;  // floats (tail: dead load)

            // ---- issue W_{t+1} DMA into bufW[cur^1], then X_{t+2} load ----
            char* bufWn = lds + (cur ^ 1) * 32768;
            __builtin_amdgcn_sched_barrier(0);
#pragma unroll
            for (int j = 0; j < 2; j++)
                GLOAD_LDS16(W16 + wsrcoff[j] + kW, bufWn + wldsoff + j * 16384);
            __builtin_amdgcn_sched_barrier(0);
            float4 xn = *(const float4*)(xsrc + kX);
            __builtin_amdgcn_sched_barrier(0);

            // ---- compute tile t from buf[cur] ----
            const char* bW = lds + cur * 32768;
            const char* bX = lds + 65536 + cur * 8192;
            h8 a[2];
#pragma unroll
            for (int mr = 0; mr < 2; mr++) {
                int row = wm * 32 + mr * 16 + l16;
                a[mr] = *(const h8*)(bX + row * 64 + ((khi ^ ((row >> 1) & 3)) << 4));
            }
#pragma unroll
            for (int nr = 0; nr < 8; nr++) {
                int row = wn * 128 + nr * 16 + l16;
                h8 bf = *(const h8*)(bW + row * 64 + ((khi ^ ((row >> 1) & 3)) << 4));
                acc[0][nr] = __builtin_amdgcn_mfma_f32_16x16x32_f16(a[0], bf, acc[0][nr], 0, 0, 0);
                acc[1][nr] = __builtin_amdgcn_mfma_f32_16x16x32_f16(a[1], bf, acc[1][nr], 0, 0, 0);
            }

            // ---- write X(t+1) (regs xu) into bufX[cur^1] ----
            {
                h4v hv = cvt4s(xu);    // waits X(t+1) (queue head after W(t+1))
                *(h4v*)(lds + 65536 + (cur ^ 1) * 8192 + xoff) = hv;
            }
            // Queue = [Wa(t+1), Wb(t+1), X(t+2)] -> vmcnt(1) certifies the
            // W-DMAs, keeps the X prefetch in flight.
            asm volatile("s_waitcnt vmcnt(1) lgkmcnt(0)" ::: "memory");
            __builtin_amdgcn_sched_barrier(0);
            __builtin_amdgcn_s_barrier();
            __builtin_amdgcn_sched_barrier(0);
            xu = xn;
        }

        // ---- epilogue: relu * colt, reduce over N ----
        float rs[2][4];
#pragma unroll
        for (int mr = 0; mr < 2; mr++)
#pragma unroll
            for (int r = 0; r < 4; r++) rs[mr][r] = 0.f;
#pragma unroll
        for (int nr = 0; nr < 8; nr++) {
            float cv = colt[b * Hh + wn * 128 + nr * 16 + l16];
#pragma unroll
            for (int mr = 0; mr < 2; mr++)
#pragma unroll
                for (int r = 0; r < 4; r++)
                    rs[mr][r] += fmaxf(acc[mr][nr][r], 0.f) * cv;
        }
#pragma unroll
        for (int mr = 0; mr < 2; mr++)
#pragma unroll
            for (int r = 0; r < 4; r++) {
                float v = rs[mr][r];
                v += __shfl_xor(v, 1);
                v += __shfl_xor(v, 2);
                v += __shfl_xor(v, 4);
                v += __shfl_xor(v, 8);
                rs[mr][r] = v;
            }
        if (l16 == 0) {
#pragma unroll
            for (int mr = 0; mr < 2; mr++)
#pragma unroll
                for (int r = 0; r < 4; r++)
                    sred[wn][wm * 32 + mr * 16 + khi * 4 + r] = rs[mr][r];
        }
        __syncthreads();
        if (tid < 128) {
            int r = r0 + tid;
            if (r < count) {
                float s = sred[0][tid] + sred[1][tid] + sred[2][tid] + sred[3][tid];
                scores[(size_t)b * Tt + crow[r]] = s;  // mask==1 here
            }
        }
        __syncthreads();   // protect sred/bufX before next work-list iteration
    }
}

// ---------------- kernel 3: masked softmax per b (IN-PLACE) + copy col -------
__global__ void softmax_kernel(const float* __restrict__ scores, const int* __restrict__ mask,
                               const float* __restrict__ col,
                               float* __restrict__ attn, float* __restrict__ out) {
    __shared__ float sm[256];
    int b = blockIdx.x, tid = threadIdx.x;
    const float* srow = scores + (size_t)b * Tt;
    const int* mrow = mask + (size_t)b * Tt;
    float v[8];
#pragma unroll
    for (int i = 0; i < 8; i++)
        v[i] = mrow[tid + i * 256] ? srow[tid + i * 256] : -1e30f;
    float mx = -1e30f;
#pragma unroll
    for (int i = 0; i < 8; i++) mx = fmaxf(mx, v[i]);
    sm[tid] = mx;
    __syncthreads();
    for (int s = 128; s > 0; s >>= 1) {
        if (tid < s) sm[tid] = fmaxf(sm[tid], sm[tid + s]);
        __syncthreads();
    }
    float M = sm[0];
    __syncthreads();
    float e[8];
    float sum = 0.f;
#pragma unroll
    for (int i = 0; i < 8; i++) {
        e[i] = __expf(v[i] - M);
        sum += e[i];
    }
    sm[tid] = sum;
    __syncthreads();
    for (int s = 128; s > 0; s >>= 1) {
        if (tid < s) sm[tid] += sm[tid + s];
        __syncthreads();
    }
    float inv = 1.f / sm[0];
    float* arow = attn + (size_t)b * Tt;
#pragma unroll
    for (int i = 0; i < 8; i++) arow[tid + i * 256] = e[i] * inv;
    for (int d = tid; d < Dd; d += 256) out[(size_t)b * 1024 + d] = col[(size_t)b * Dd + d];
}

// ---------------- kernel 4: weighted sums over COMPACTED t -------------------
// MEASUREMENT this round: launched twice (idempotent — writes only part[] as a
// pure function of attn/X/cidx/cnt). wsum_dur = total_R14 - 233. Remove next.
__global__ void wsum_kernel(const float* __restrict__ attn, const float* __restrict__ X,
                            const int* __restrict__ cidx, const int* __restrict__ cnt,
                            float* __restrict__ part) {
    int dh = blockIdx.x;   // 0..1
    int tc = blockIdx.y;   // 0..3
    int b  = blockIdx.z;   // 0..127
    int tid = threadIdx.x; // 256
    int d = dh * 256 + tid;
    int count = cnt[b];
    int base = tc * 512;
    int lim = count - base; if (lim > 512) lim = 512; if (lim < 0) lim = 0;
    __shared__ float sa[512];
    __shared__ int  sidx[512];
    const int* crow = cidx + (size_t)b * Tt;
    for (int j = tid; j < 512; j += 256) {
        int r = base + j;
        bool v = r < count;
        int t = v ? crow[r] : 0;
        sidx[j] = t;
        sa[j] = v ? attn[(size_t)b * Tt + t] : 0.f;
    }
    __syncthreads();
    float acc = 0.f;
    const float* xb = X + (size_t)b * Tt * Dd + d;
#pragma unroll 4
    for (int j = 0; j < lim; j++) acc += sa[j] * xb[(size_t)sidx[j] * Dd];
    part[((size_t)b * 4 + tc) * Dd + d] = acc;
}

// ---------------- kernel 5: combine partials, write both outputs ----------------
__global__ void combine_kernel(const float* __restrict__ part, float* __restrict__ out) {
    int i = blockIdx.x * 256 + threadIdx.x;  // < 65536
    int b = i >> 9, d = i & 511;
    float s = 0.f;
#pragma unroll
    for (int tc = 0; tc < 4; tc++) s += part[((size_t)b * 4 + tc) * Dd + d];
    out[(size_t)b * 1024 + 512 + d] = s;                 // cat section, second half
    out[(size_t)Bb * 1024 + (size_t)b * 512 + d] = s;    // attention_output section
}

extern "C" void kernel_launch(void* const* d_in, const int* in_sizes, int n_in,
                              void* d_out, int out_size, void* d_ws, size_t ws_size,
                              hipStream_t stream) {
    const float* col  = (const float*)d_in[0];   // [128,512]
    const float* X    = (const float*)d_in[1];   // [128,2048,512]
    const int*   mask = (const int*)d_in[2];     // [128,2048]
    const float* W    = (const float*)d_in[3];   // [512,512]
    float* out = (float*)d_out;

    char* ws = (char*)d_ws;
    _Float16* W16   = (_Float16*)ws;                     // 0    .. 512K
    float*    colt  = (float*)(ws + (512 << 10));        // 512K .. 768K
    float*    scores= (float*)(ws + (768 << 10));        // 768K .. 1792K
    float*    attn  = scores;                            // softmax in-place
    float*    part  = (float*)(ws + (1792 << 10));       // 1792K.. 2816K
    int*      cidx  = (int*)(ws + (2816 << 10));         // 2816K.. 3840K
    int*      cnt   = (int*)(ws + (3840 << 10));         // 3840K.. +512B
    int*      tlist = (int*)(ws + (3841 << 10));         // 3841K.. +16KB
    int*      ntile = (int*)(ws + (3860 << 10));         // 3860K.. +4B

    hipMemsetAsync(ntile, 0, 4, stream);
    hipLaunchKernelGGL(prep_kernel, dim3(1408), dim3(256), 0, stream,
                       W, W16, mask, cidx, cnt, tlist, ntile, col, colt);
    hipLaunchKernelGGL(scores_kernel, dim3(NG), dim3(1024), 0, stream,
                       X, W16, colt, cidx, cnt, tlist, ntile, scores);
    hipLaunchKernelGGL(softmax_kernel, dim3(Bb), dim3(256), 0, stream, scores, mask, col, attn, out);
    // MEASUREMENT: wsum launched twice (idempotent). wsum_dur = total - 233.
    hipLaunchKernelGGL(wsum_kernel, dim3(2, 4, Bb), dim3(256), 0, stream, attn, X, cidx, cnt, part);
    hipLaunchKernelGGL(wsum_kernel, dim3(2, 4, Bb), dim3(256), 0, stream, attn, X, cidx, cnt, part);
    hipLaunchKernelGGL(combine_kernel, dim3(65536 / 256), dim3(256), 0, stream, part, out);
}

// Round 15
// 229.248 us; speedup vs baseline: 1.3744x; 1.3744x over previous
//
#include <hip/hip_runtime.h>
#include <cstdint>
#include <cstddef>

#define Bb 128
#define Tt 2048
#define Dd 512
#define Hh 512
#define Mtot (Bb*Tt)
#define NG 1152   // scores grid; grid-stride covers pathological masks

typedef __attribute__((ext_vector_type(8))) _Float16 h8;
typedef __attribute__((ext_vector_type(4))) _Float16 h4v;
typedef __attribute__((ext_vector_type(4))) float f4;

// Direct global->LDS DMA, 16B per lane. LDS dest is WAVE-UNIFORM base; HW
// writes lane l at base + l*16. Global src is per-lane (pre-swizzled).
#define GLOAD_LDS16(gsrc, ldst) \
    __builtin_amdgcn_global_load_lds((const __attribute__((address_space(1))) void*)(gsrc), \
                                     (__attribute__((address_space(3))) void*)(ldst), 16, 0, 0)

__device__ __forceinline__ h4v cvt4s(const float4 a) {
    h4v h;
    h[0] = (_Float16)a.x; h[1] = (_Float16)a.y;
    h[2] = (_Float16)a.z; h[3] = (_Float16)a.w;
    return h;
}

// ---------------- kernel 1: fused prep ----------------
__global__ __launch_bounds__(256) void prep_kernel(
    const float* __restrict__ W, _Float16* __restrict__ W16,
    const int* __restrict__ mask, int* __restrict__ cidx, int* __restrict__ cnt,
    int* __restrict__ tlist, int* __restrict__ ntiles,
    const float* __restrict__ col, float* __restrict__ colt)
{
    const int blk = blockIdx.x, tid = threadIdx.x;
    if (blk < 1024) {                       // ---- W16 cast ----
        int i = blk * 256 + tid;
        W16[i] = (_Float16)W[i];
        return;
    }
    if (blk < 1152) {                       // ---- compaction (b = blk-1024) ----
        __shared__ int wsum[4];
        int b = blk - 1024;
        const int* mrow = mask + (size_t)b * Tt;
        int mv[8], c = 0;
#pragma unroll
        for (int i = 0; i < 8; i++) {
            mv[i] = mrow[tid * 8 + i];
            c += mv[i];
        }
        int lane = tid & 63, wv = tid >> 6;
        int inc = c;
#pragma unroll
        for (int off = 1; off < 64; off <<= 1) {
            int n = __shfl_up(inc, off);
            if (lane >= off) inc += n;
        }
        if (lane == 63) wsum[wv] = inc;
        __syncthreads();
        int wbase = 0;
        for (int w = 0; w < wv; w++) wbase += wsum[w];
        int pos = wbase + inc - c;          // exclusive prefix
        int* crow = cidx + (size_t)b * Tt;
#pragma unroll
        for (int i = 0; i < 8; i++)
            if (mv[i]) crow[pos++] = tid * 8 + i;
        if (tid == 255) {
            int total = wbase + inc;
            cnt[b] = total;
            int nt = (total + 127) >> 7;    // tiles of 128 rows
            int base = atomicAdd(ntiles, nt);
            for (int i = 0; i < nt; i++) tlist[base + i] = (b << 8) | i;
        }
        return;
    }
    {                                        // ---- col_proj ----
        __shared__ float c[Dd];
        int idx = blk - 1152;
        int b = idx >> 1;
        int h = (idx & 1) * 256 + tid;
        c[tid] = col[b * Dd + tid];
        c[tid + 256] = col[b * Dd + 256 + tid];
        __syncthreads();
        const f4* w4 = (const f4*)(W + (size_t)h * Dd);
        float acc = 0.f;
#pragma unroll 8
        for (int k = 0; k < Dd / 4; k++) {
            f4 w = w4[k];
            acc += w.x * c[4 * k] + w.y * c[4 * k + 1] + w.z * c[4 * k + 2] + w.w * c[4 * k + 3];
        }
        colt[b * Hh + h] = fmaxf(acc, 0.f);
    }
}

// ---------------- kernel 2: scores GEMM — R9 EXACT (measured 125.5us) --------
__global__ __launch_bounds__(1024, 4) void scores_kernel(
    const float* __restrict__ X,        // [B*T][512]
    const _Float16* __restrict__ W16,   // [512][512]
    const float* __restrict__ colt,     // [128][512]
    const int* __restrict__ cidx,       // [B][T]
    const int* __restrict__ cnt,        // [B]
    const int* __restrict__ tlist,      // work list: (b<<8)|tile
    const int* __restrict__ ntiles,     // [1]
    float* __restrict__ scores)         // [B*T] (masked entries untouched)
{
    const int tid = threadIdx.x;
    const int total = ntiles[0];

    // LDS: bufW 2x32KB @0/32768; bufX 2x8KB @65536/73728; sred[4][128] (2KB)
    // aliases bufX[0] (written only after the final barrier). Total 80KB.
    __shared__ __align__(16) char lds[81920];
    float (*sred)[128] = (float(*)[128])(lds + 65536);

    const int wave = tid >> 6;
    const int lane = tid & 63;
    const int wm = wave >> 2;   // 0..3 : M quarter (rows wm*32..+32)
    const int wn = wave & 3;    // 0..3 : N strip (cols wn*128..+128)
    const int l16 = lane & 15;
    const int khi = lane >> 4;  // 0..3

    int wsrcoff[2];
#pragma unroll
    for (int j = 0; j < 2; j++) {
        int r = (j * 16 + wave) * 16 + (lane >> 2);
        int c = (lane & 3) ^ ((r >> 1) & 3);
        wsrcoff[j] = r * Dd + c * 8;
    }
    const int wldsoff = wave * 1024;   // + j*16384 per chunk-call

    const int xrow = tid >> 3, xf4 = tid & 7;
    const int xoff = xrow * 64 + (((xf4 >> 1) ^ ((xrow >> 1) & 3)) << 4) + (xf4 & 1) * 8;

    for (int idx = blockIdx.x; idx < total; idx += NG) {
        const int ent = tlist[idx];
        const int b = ent >> 8;
        const int tile = ent & 255;
        const int count = cnt[b];
        const int r0 = tile * 128;

        const int* crow = cidx + (size_t)b * Tt;
        int rl = r0 + xrow; if (rl >= count) rl = count - 1;  // clamp (dup, never stored)
        const float* xsrc = X + ((size_t)b * Tt + crow[rl]) * Dd + xf4 * 4;

        f4 acc[2][8];
#pragma unroll
        for (int i = 0; i < 2; i++)
#pragma unroll
            for (int j = 0; j < 8; j++) {
                f4 z = {0.f, 0.f, 0.f, 0.f};
                acc[i][j] = z;
            }

        // ---- prologue: W_0 DMA -> bufW0; X_0 -> LDS; X_1 -> regs ----
        __builtin_amdgcn_sched_barrier(0);
#pragma unroll
        for (int j = 0; j < 2; j++)
            GLOAD_LDS16(W16 + wsrcoff[j], lds + wldsoff + j * 16384);
        __builtin_amdgcn_sched_barrier(0);
        float4 x0 = *(const float4*)(xsrc);
        float4 xu = *(const float4*)(xsrc + 32);
        __builtin_amdgcn_sched_barrier(0);
        {
            h4v hv = cvt4s(x0);        // waits x0 -> drains W_0 DMAs too (in-order)
            *(h4v*)(lds + 65536 + xoff) = hv;
        }
        asm volatile("s_waitcnt vmcnt(1) lgkmcnt(0)" ::: "memory");
        __builtin_amdgcn_sched_barrier(0);
        __builtin_amdgcn_s_barrier();
        __builtin_amdgcn_sched_barrier(0);

#pragma unroll 2
        for (int t = 0; t < 16; ++t) {
            const int cur = t & 1;
            const int kW = (t < 15 ? t + 1 : 15) * 32;  // halfs (tail: dead re-stage)
            const int kX = (t < 14 ? t + 2 : 15) * 32;  // floats (tail: dead load)

            // ---- issue W_{t+1} DMA into bufW[cur^1], then X_{t+2} load ----
            char* bufWn = lds + (cur ^ 1) * 32768;
            __builtin_amdgcn_sched_barrier(0);
#pragma unroll
            for (int j = 0; j < 2; j++)
                GLOAD_LDS16(W16 + wsrcoff[j] + kW, bufWn + wldsoff + j * 16384);
            __builtin_amdgcn_sched_barrier(0);
            float4 xn = *(const float4*)(xsrc + kX);
            __builtin_amdgcn_sched_barrier(0);

            // ---- compute tile t from buf[cur] ----
            const char* bW = lds + cur * 32768;
            const char* bX = lds + 65536 + cur * 8192;
            h8 a[2];
#pragma unroll
            for (int mr = 0; mr < 2; mr++) {
                int row = wm * 32 + mr * 16 + l16;
                a[mr] = *(const h8*)(bX + row * 64 + ((khi ^ ((row >> 1) & 3)) << 4));
            }
#pragma unroll
            for (int nr = 0; nr < 8; nr++) {
                int row = wn * 128 + nr * 16 + l16;
                h8 bf = *(const h8*)(bW + row * 64 + ((khi ^ ((row >> 1) & 3)) << 4));
                acc[0][nr] = __builtin_amdgcn_mfma_f32_16x16x32_f16(a[0], bf, acc[0][nr], 0, 0, 0);
                acc[1][nr] = __builtin_amdgcn_mfma_f32_16x16x32_f16(a[1], bf, acc[1][nr], 0, 0, 0);
            }

            // ---- write X(t+1) (regs xu) into bufX[cur^1] ----
            {
                h4v hv = cvt4s(xu);    // waits X(t+1) (queue head after W(t+1))
                *(h4v*)(lds + 65536 + (cur ^ 1) * 8192 + xoff) = hv;
            }
            // Queue = [Wa(t+1), Wb(t+1), X(t+2)] -> vmcnt(1) certifies the
            // W-DMAs, keeps the X prefetch in flight.
            asm volatile("s_waitcnt vmcnt(1) lgkmcnt(0)" ::: "memory");
            __builtin_amdgcn_sched_barrier(0);
            __builtin_amdgcn_s_barrier();
            __builtin_amdgcn_sched_barrier(0);
            xu = xn;
        }

        // ---- epilogue: relu * colt, reduce over N ----
        float rs[2][4];
#pragma unroll
        for (int mr = 0; mr < 2; mr++)
#pragma unroll
            for (int r = 0; r < 4; r++) rs[mr][r] = 0.f;
#pragma unroll
        for (int nr = 0; nr < 8; nr++) {
            float cv = colt[b * Hh + wn * 128 + nr * 16 + l16];
#pragma unroll
            for (int mr = 0; mr < 2; mr++)
#pragma unroll
                for (int r = 0; r < 4; r++)
                    rs[mr][r] += fmaxf(acc[mr][nr][r], 0.f) * cv;
        }
#pragma unroll
        for (int mr = 0; mr < 2; mr++)
#pragma unroll
            for (int r = 0; r < 4; r++) {
                float v = rs[mr][r];
                v += __shfl_xor(v, 1);
                v += __shfl_xor(v, 2);
                v += __shfl_xor(v, 4);
                v += __shfl_xor(v, 8);
                rs[mr][r] = v;
            }
        if (l16 == 0) {
#pragma unroll
            for (int mr = 0; mr < 2; mr++)
#pragma unroll
                for (int r = 0; r < 4; r++)
                    sred[wn][wm * 32 + mr * 16 + khi * 4 + r] = rs[mr][r];
        }
        __syncthreads();
        if (tid < 128) {
            int r = r0 + tid;
            if (r < count) {
                float s = sred[0][tid] + sred[1][tid] + sred[2][tid] + sred[3][tid];
                scores[(size_t)b * Tt + crow[r]] = s;  // mask==1 here
            }
        }
        __syncthreads();   // protect sred/bufX before next work-list iteration
    }
}

// ---------------- kernel 3: masked softmax per b (IN-PLACE) + copy col -------
__global__ void softmax_kernel(const float* __restrict__ scores, const int* __restrict__ mask,
                               const float* __restrict__ col,
                               float* __restrict__ attn, float* __restrict__ out) {
    __shared__ float sm[256];
    int b = blockIdx.x, tid = threadIdx.x;
    const float* srow = scores + (size_t)b * Tt;
    const int* mrow = mask + (size_t)b * Tt;
    float v[8];
#pragma unroll
    for (int i = 0; i < 8; i++)
        v[i] = mrow[tid + i * 256] ? srow[tid + i * 256] : -1e30f;
    float mx = -1e30f;
#pragma unroll
    for (int i = 0; i < 8; i++) mx = fmaxf(mx, v[i]);
    sm[tid] = mx;
    __syncthreads();
    for (int s = 128; s > 0; s >>= 1) {
        if (tid < s) sm[tid] = fmaxf(sm[tid], sm[tid + s]);
        __syncthreads();
    }
    float M = sm[0];
    __syncthreads();
    float e[8];
    float sum = 0.f;
#pragma unroll
    for (int i = 0; i < 8; i++) {
        e[i] = __expf(v[i] - M);
        sum += e[i];
    }
    sm[tid] = sum;
    __syncthreads();
    for (int s = 128; s > 0; s >>= 1) {
        if (tid < s) sm[tid] += sm[tid + s];
        __syncthreads();
    }
    float inv = 1.f / sm[0];
    float* arow = attn + (size_t)b * Tt;
#pragma unroll
    for (int i = 0; i < 8; i++) arow[tid + i * 256] = e[i] * inv;
    for (int d = tid; d < Dd; d += 256) out[(size_t)b * 1024 + d] = col[(size_t)b * Dd + d];
}

// ---------------- kernel 4: weighted sums, float4 lanes, 8 row-chunks --------
// RESTRUCTURED (R14 measured 82us = 3.3 TB/s, 52% of achievable -- too few
// bytes in flight). Now: cg=tid&127 owns float4 d-slice (128 lanes x 16B =
// full 2KB row per issue), rs=tid>>7 gives 2 interleaved row streams, unroll 4
// -> 4x16B loads in flight per thread. Grid 8x128 = 1024 blocks.
__global__ __launch_bounds__(256) void wsum_kernel(
    const float* __restrict__ attn, const float* __restrict__ X,
    const int* __restrict__ cidx, const int* __restrict__ cnt,
    float* __restrict__ part) {
    int tc = blockIdx.x;   // 0..7
    int b  = blockIdx.y;   // 0..127
    int tid = threadIdx.x; // 256
    int count = cnt[b];
    int base = tc * 256;
    int lim = count - base; if (lim > 256) lim = 256; if (lim < 0) lim = 0;
    __shared__ float sa[256];
    __shared__ int  sidx[256];
    __shared__ float red[512];
    const int* crow = cidx + (size_t)b * Tt;
    {
        int r = base + tid;
        bool v = r < count;
        int t = v ? crow[r] : 0;
        sidx[tid] = t;
        sa[tid] = v ? attn[(size_t)b * Tt + t] : 0.f;
    }
    __syncthreads();
    const int cg = tid & 127, rs = tid >> 7;
    float ax = 0.f, ay = 0.f, az = 0.f, aw = 0.f;
    const float* xb = X + (size_t)b * Tt * Dd + cg * 4;
#pragma unroll 4
    for (int j = rs; j < lim; j += 2) {
        const float4 xv = *(const float4*)(xb + (size_t)sidx[j] * Dd);
        float s = sa[j];
        ax += s * xv.x; ay += s * xv.y; az += s * xv.z; aw += s * xv.w;
    }
    if (rs == 1) {
        float4 st = {ax, ay, az, aw};
        *(float4*)(red + cg * 4) = st;
    }
    __syncthreads();
    if (rs == 0) {
        const float4 o = *(const float4*)(red + cg * 4);
        float4 st = {ax + o.x, ay + o.y, az + o.z, aw + o.w};
        *(float4*)(part + ((size_t)b * 8 + tc) * Dd + cg * 4) = st;
    }
}

// ---------------- kernel 5: combine 8 partials, write both outputs -----------
__global__ void combine_kernel(const float* __restrict__ part, float* __restrict__ out) {
    int i = blockIdx.x * 256 + threadIdx.x;  // < 65536
    int b = i >> 9, d = i & 511;
    float s = 0.f;
#pragma unroll
    for (int tc = 0; tc < 8; tc++) s += part[((size_t)b * 8 + tc) * Dd + d];
    out[(size_t)b * 1024 + 512 + d] = s;                 // cat section, second half
    out[(size_t)Bb * 1024 + (size_t)b * 512 + d] = s;    // attention_output section
}

extern "C" void kernel_launch(void* const* d_in, const int* in_sizes, int n_in,
                              void* d_out, int out_size, void* d_ws, size_t ws_size,
                              hipStream_t stream) {
    const float* col  = (const float*)d_in[0];   // [128,512]
    const float* X    = (const float*)d_in[1];   // [128,2048,512]
    const int*   mask = (const int*)d_in[2];     // [128,2048]
    const float* W    = (const float*)d_in[3];   // [512,512]
    float* out = (float*)d_out;

    char* ws = (char*)d_ws;
    _Float16* W16   = (_Float16*)ws;                     // 0    .. 512K
    float*    colt  = (float*)(ws + (512 << 10));        // 512K .. 768K
    float*    scores= (float*)(ws + (768 << 10));        // 768K .. 1792K
    float*    attn  = scores;                            // softmax in-place
    float*    part  = (float*)(ws + (1792 << 10));       // 1792K.. 3840K (2MB, 8 chunks)
    int*      cidx  = (int*)(ws + (3840 << 10));         // 3840K.. 4864K
    int*      cnt   = (int*)(ws + (4864 << 10));         // 4864K.. +512B
    int*      tlist = (int*)(ws + (4865 << 10));         // 4865K.. +16KB
    int*      ntile = (int*)(ws + (4884 << 10));         // 4884K.. +4B

    hipMemsetAsync(ntile, 0, 4, stream);
    hipLaunchKernelGGL(prep_kernel, dim3(1408), dim3(256), 0, stream,
                       W, W16, mask, cidx, cnt, tlist, ntile, col, colt);
    hipLaunchKernelGGL(scores_kernel, dim3(NG), dim3(1024), 0, stream,
                       X, W16, colt, cidx, cnt, tlist, ntile, scores);
    hipLaunchKernelGGL(softmax_kernel, dim3(Bb), dim3(256), 0, stream, scores, mask, col, attn, out);
    hipLaunchKernelGGL(wsum_kernel, dim3(8, Bb), dim3(256), 0, stream, attn, X, cidx, cnt, part);
    hipLaunchKernelGGL(combine_kernel, dim3(65536 / 256), dim3(256), 0, stream, part, out);
}

// Round 16
// 183.928 us; speedup vs baseline: 1.7131x; 1.2464x over previous
//
#include <hip/hip_runtime.h>
#include <cstdint>
#include <cstddef>

#define Bb 128
#define Tt 2048
#define Dd 512
#define Hh 512
#define Mtot (Bb*Tt)
#define NG 1152   // scores grid; grid-stride covers pathological masks

typedef __attribute__((ext_vector_type(8))) _Float16 h8;
typedef __attribute__((ext_vector_type(4))) _Float16 h4v;
typedef __attribute__((ext_vector_type(4))) float f4;

// Direct global->LDS DMA, 16B per lane. LDS dest is WAVE-UNIFORM base; HW
// writes lane l at base + l*16. Global src is per-lane (pre-swizzled).
#define GLOAD_LDS16(gsrc, ldst) \
    __builtin_amdgcn_global_load_lds((const __attribute__((address_space(1))) void*)(gsrc), \
                                     (__attribute__((address_space(3))) void*)(ldst), 16, 0, 0)

__device__ __forceinline__ h4v cvt4s(const float4 a) {
    h4v h;
    h[0] = (_Float16)a.x; h[1] = (_Float16)a.y;
    h[2] = (_Float16)a.z; h[3] = (_Float16)a.w;
    return h;
}

// ---------------- kernel 1: fused prep (unchanged from R15) ----------------
__global__ __launch_bounds__(256) void prep_kernel(
    const float* __restrict__ W, _Float16* __restrict__ W16,
    const int* __restrict__ mask, int* __restrict__ cidx, int* __restrict__ cnt,
    int* __restrict__ tlist, int* __restrict__ ntiles,
    const float* __restrict__ col, float* __restrict__ colt)
{
    const int blk = blockIdx.x, tid = threadIdx.x;
    if (blk < 1024) {                       // ---- W16 cast ----
        int i = blk * 256 + tid;
        W16[i] = (_Float16)W[i];
        return;
    }
    if (blk < 1152) {                       // ---- compaction (b = blk-1024) ----
        __shared__ int wsum[4];
        int b = blk - 1024;
        const int* mrow = mask + (size_t)b * Tt;
        int mv[8], c = 0;
#pragma unroll
        for (int i = 0; i < 8; i++) {
            mv[i] = mrow[tid * 8 + i];
            c += mv[i];
        }
        int lane = tid & 63, wv = tid >> 6;
        int inc = c;
#pragma unroll
        for (int off = 1; off < 64; off <<= 1) {
            int n = __shfl_up(inc, off);
            if (lane >= off) inc += n;
        }
        if (lane == 63) wsum[wv] = inc;
        __syncthreads();
        int wbase = 0;
        for (int w = 0; w < wv; w++) wbase += wsum[w];
        int pos = wbase + inc - c;          // exclusive prefix
        int* crow = cidx + (size_t)b * Tt;
#pragma unroll
        for (int i = 0; i < 8; i++)
            if (mv[i]) crow[pos++] = tid * 8 + i;
        if (tid == 255) {
            int total = wbase + inc;
            cnt[b] = total;
            int nt = (total + 127) >> 7;    // tiles of 128 rows
            int base = atomicAdd(ntiles, nt);
            for (int i = 0; i < nt; i++) tlist[base + i] = (b << 8) | i;
        }
        return;
    }
    {                                        // ---- col_proj ----
        __shared__ float c[Dd];
        int idx = blk - 1152;
        int b = idx >> 1;
        int h = (idx & 1) * 256 + tid;
        c[tid] = col[b * Dd + tid];
        c[tid + 256] = col[b * Dd + 256 + tid];
        __syncthreads();
        const f4* w4 = (const f4*)(W + (size_t)h * Dd);
        float acc = 0.f;
#pragma unroll 8
        for (int k = 0; k < Dd / 4; k++) {
            f4 w = w4[k];
            acc += w.x * c[4 * k] + w.y * c[4 * k + 1] + w.z * c[4 * k + 2] + w.w * c[4 * k + 3];
        }
        colt[b * Hh + h] = fmaxf(acc, 0.f);
    }
}

// ---------------- kernel 2: scores GEMM + FLASH partial (fused) -------------
// GEMM part = R9 exact (measured 125.5us). NEW epilogue per (b,tile):
//   m_i = max(s), w_r = e^{s_r - m_i} (0 for padded rows), l_i = sum(w),
//   psum_i[512] = sum_r w_r * X[row_r][:]  (X re-read; L2/L3-warm)
// Standalone softmax/wsum/combine kernels are absorbed (removes the 78us
// dedicated HBM gather). LDS reuse audit:
//   red[8][512] @0 (bufW0): last DMA into bufW0 is the dead t=15 prefetch,
//     retired by t=15's vmcnt(1) before its barrier -> safe to overwrite.
//   srow/wrow/sidx2/scr @67584.. (inside bufX[0]): bufX[0]'s dead t=15
//     ds_write is ordered by lgkmcnt(0)+barrier -> safe.
//   Next grid-stride iteration re-stages bufW0/bufX0 only after the loop-end
//   __syncthreads().
__global__ __launch_bounds__(1024, 4) void scores_kernel(
    const float* __restrict__ X,        // [B*T][512]
    const _Float16* __restrict__ W16,   // [512][512]
    const float* __restrict__ colt,     // [128][512]
    const int* __restrict__ cidx,       // [B][T]
    const int* __restrict__ cnt,        // [B]
    const int* __restrict__ tlist,      // work list: (b<<8)|tile
    const int* __restrict__ ntiles,     // [1]
    float* __restrict__ pm,             // [128*16] tile max
    float* __restrict__ pl,             // [128*16] tile exp-sum
    float* __restrict__ psum)           // [128*16][512] weighted X partials
{
    const int tid = threadIdx.x;
    const int total = ntiles[0];

    __shared__ __align__(16) char lds[81920];
    float (*sred)[128] = (float(*)[128])(lds + 65536);
    float* srow  = (float*)(lds + 67584);   // [128]
    float* wrow  = (float*)(lds + 68096);   // [128]
    int*   sidx2 = (int*)  (lds + 68608);   // [128]
    float* scr   = (float*)(lds + 69120);   // [4]
    float* red   = (float*)lds;             // [8][512] aliases bufW0

    const int wave = tid >> 6;
    const int lane = tid & 63;
    const int wm = wave >> 2;   // 0..3 : M quarter
    const int wn = wave & 3;    // 0..3 : N strip
    const int l16 = lane & 15;
    const int khi = lane >> 4;  // 0..3

    int wsrcoff[2];
#pragma unroll
    for (int j = 0; j < 2; j++) {
        int r = (j * 16 + wave) * 16 + (lane >> 2);
        int c = (lane & 3) ^ ((r >> 1) & 3);
        wsrcoff[j] = r * Dd + c * 8;
    }
    const int wldsoff = wave * 1024;   // + j*16384 per chunk-call

    const int xrow = tid >> 3, xf4 = tid & 7;
    const int xoff = xrow * 64 + (((xf4 >> 1) ^ ((xrow >> 1) & 3)) << 4) + (xf4 & 1) * 8;

    for (int idx = blockIdx.x; idx < total; idx += NG) {
        const int ent = tlist[idx];
        const int b = ent >> 8;
        const int tile = ent & 255;
        const int count = cnt[b];
        const int r0 = tile * 128;

        const int* crow = cidx + (size_t)b * Tt;
        int rl = r0 + xrow; if (rl >= count) rl = count - 1;  // clamp (dup, never stored)
        const float* xsrc = X + ((size_t)b * Tt + crow[rl]) * Dd + xf4 * 4;

        f4 acc[2][8];
#pragma unroll
        for (int i = 0; i < 2; i++)
#pragma unroll
            for (int j = 0; j < 8; j++) {
                f4 z = {0.f, 0.f, 0.f, 0.f};
                acc[i][j] = z;
            }

        // ---- prologue: W_0 DMA -> bufW0; X_0 -> LDS; X_1 -> regs ----
        __builtin_amdgcn_sched_barrier(0);
#pragma unroll
        for (int j = 0; j < 2; j++)
            GLOAD_LDS16(W16 + wsrcoff[j], lds + wldsoff + j * 16384);
        __builtin_amdgcn_sched_barrier(0);
        float4 x0 = *(const float4*)(xsrc);
        float4 xu = *(const float4*)(xsrc + 32);
        __builtin_amdgcn_sched_barrier(0);
        {
            h4v hv = cvt4s(x0);        // waits x0 -> drains W_0 DMAs too (in-order)
            *(h4v*)(lds + 65536 + xoff) = hv;
        }
        asm volatile("s_waitcnt vmcnt(1) lgkmcnt(0)" ::: "memory");
        __builtin_amdgcn_sched_barrier(0);
        __builtin_amdgcn_s_barrier();
        __builtin_amdgcn_sched_barrier(0);

#pragma unroll 2
        for (int t = 0; t < 16; ++t) {
            const int cur = t & 1;
            const int kW = (t < 15 ? t + 1 : 15) * 32;  // halfs (tail: dead re-stage)
            const int kX = (t < 14 ? t + 2 : 15) * 32;  // floats (tail: dead load)

            // ---- issue W_{t+1} DMA into bufW[cur^1], then X_{t+2} load ----
            char* bufWn = lds + (cur ^ 1) * 32768;
            __builtin_amdgcn_sched_barrier(0);
#pragma unroll
            for (int j = 0; j < 2; j++)
                GLOAD_LDS16(W16 + wsrcoff[j] + kW, bufWn + wldsoff + j * 16384);
            __builtin_amdgcn_sched_barrier(0);
            float4 xn = *(const float4*)(xsrc + kX);
            __builtin_amdgcn_sched_barrier(0);

            // ---- compute tile t from buf[cur] ----
            const char* bW = lds + cur * 32768;
            const char* bX = lds + 65536 + cur * 8192;
            h8 a[2];
#pragma unroll
            for (int mr = 0; mr < 2; mr++) {
                int row = wm * 32 + mr * 16 + l16;
                a[mr] = *(const h8*)(bX + row * 64 + ((khi ^ ((row >> 1) & 3)) << 4));
            }
#pragma unroll
            for (int nr = 0; nr < 8; nr++) {
                int row = wn * 128 + nr * 16 + l16;
                h8 bf = *(const h8*)(bW + row * 64 + ((khi ^ ((row >> 1) & 3)) << 4));
                acc[0][nr] = __builtin_amdgcn_mfma_f32_16x16x32_f16(a[0], bf, acc[0][nr], 0, 0, 0);
                acc[1][nr] = __builtin_amdgcn_mfma_f32_16x16x32_f16(a[1], bf, acc[1][nr], 0, 0, 0);
            }

            // ---- write X(t+1) (regs xu) into bufX[cur^1] ----
            {
                h4v hv = cvt4s(xu);    // waits X(t+1) (queue head after W(t+1))
                *(h4v*)(lds + 65536 + (cur ^ 1) * 8192 + xoff) = hv;
            }
            // Queue = [Wa(t+1), Wb(t+1), X(t+2)] -> vmcnt(1) certifies the
            // W-DMAs, keeps the X prefetch in flight.
            asm volatile("s_waitcnt vmcnt(1) lgkmcnt(0)" ::: "memory");
            __builtin_amdgcn_sched_barrier(0);
            __builtin_amdgcn_s_barrier();
            __builtin_amdgcn_sched_barrier(0);
            xu = xn;
        }

        // ---- epilogue 1: relu * colt, reduce over N -> sred ----
        float rs[2][4];
#pragma unroll
        for (int mr = 0; mr < 2; mr++)
#pragma unroll
            for (int r = 0; r < 4; r++) rs[mr][r] = 0.f;
#pragma unroll
        for (int nr = 0; nr < 8; nr++) {
            float cv = colt[b * Hh + wn * 128 + nr * 16 + l16];
#pragma unroll
            for (int mr = 0; mr < 2; mr++)
#pragma unroll
                for (int r = 0; r < 4; r++)
                    rs[mr][r] += fmaxf(acc[mr][nr][r], 0.f) * cv;
        }
#pragma unroll
        for (int mr = 0; mr < 2; mr++)
#pragma unroll
            for (int r = 0; r < 4; r++) {
                float v = rs[mr][r];
                v += __shfl_xor(v, 1);
                v += __shfl_xor(v, 2);
                v += __shfl_xor(v, 4);
                v += __shfl_xor(v, 8);
                rs[mr][r] = v;
            }
        if (l16 == 0) {
#pragma unroll
            for (int mr = 0; mr < 2; mr++)
#pragma unroll
                for (int r = 0; r < 4; r++)
                    sred[wn][wm * 32 + mr * 16 + khi * 4 + r] = rs[mr][r];
        }
        __syncthreads();

        // ---- epilogue 2: flash partial (m_i, w, l_i) ----
        if (tid < 128) {
            int r = r0 + tid;
            bool valid = r < count;
            float s = sred[0][tid] + sred[1][tid] + sred[2][tid] + sred[3][tid];
            s = valid ? s : -1e30f;
            srow[tid] = s;
            sidx2[tid] = crow[valid ? r : (count - 1)];
            float mv = s;
#pragma unroll
            for (int off = 1; off < 64; off <<= 1) mv = fmaxf(mv, __shfl_xor(mv, off));
            if (lane == 0) scr[wave] = mv;   // wave in {0,1} here
        }
        __syncthreads();
        const float mloc = fmaxf(scr[0], scr[1]);
        if (tid < 128) {
            float s = srow[tid];
            float e = (s > -1e29f) ? __expf(s - mloc) : 0.f;
            wrow[tid] = e;
#pragma unroll
            for (int off = 1; off < 64; off <<= 1) e += __shfl_xor(e, off);
            if (lane == 0) scr[2 + wave] = e;
        }
        __syncthreads();
        if (tid == 0) {
            pm[(b << 4) + tile] = mloc;
            pl[(b << 4) + tile] = scr[2] + scr[3];
        }

        // ---- epilogue 3: weighted X repass -> psum ----
        {
            const int rgrp = tid >> 7;      // 0..7
            const int cg = tid & 127;       // float4 col slice
            float ax = 0.f, ay = 0.f, az = 0.f, aw = 0.f;
            const float* xb2 = X + (size_t)b * Tt * Dd + cg * 4;
#pragma unroll 4
            for (int r = rgrp; r < 128; r += 8) {
                const float4 xv = *(const float4*)(xb2 + (size_t)sidx2[r] * Dd);
                float wv = wrow[r];         // 0 for padded rows
                ax += wv * xv.x; ay += wv * xv.y; az += wv * xv.z; aw += wv * xv.w;
            }
            float4 st = {ax, ay, az, aw};
            *(float4*)(red + rgrp * 512 + cg * 4) = st;
        }
        __syncthreads();
        if (tid < 128) {
            int cg = tid;
            float ax = 0.f, ay = 0.f, az = 0.f, aw = 0.f;
#pragma unroll
            for (int g = 0; g < 8; g++) {
                const float4 v = *(const float4*)(red + g * 512 + cg * 4);
                ax += v.x; ay += v.y; az += v.z; aw += v.w;
            }
            float4 st = {ax, ay, az, aw};
            *(float4*)(psum + ((size_t)((b << 4) + tile)) * Dd + cg * 4) = st;
        }
        __syncthreads();   // protect red/scratch/bufW0 before next iteration
    }
}

// ---------------- kernel 3: final combine per b ------------------------------
// M = max m_i; L = sum l_i e^{m_i-M}; out = (sum psum_i e^{m_i-M}) / L.
// Also writes the col copy. nt <= 16.
__global__ __launch_bounds__(256) void final_kernel(
    const float* __restrict__ pm, const float* __restrict__ pl,
    const float* __restrict__ psum, const int* __restrict__ cnt,
    const float* __restrict__ col, float* __restrict__ out)
{
    __shared__ float e[16];
    __shared__ float Linv;
    int b = blockIdx.x, tid = threadIdx.x;
    int nt = (cnt[b] + 127) >> 7;
    if (tid == 0) {
        float M = -1e30f;
        for (int i = 0; i < nt; i++) M = fmaxf(M, pm[(b << 4) + i]);
        float L = 0.f;
        for (int i = 0; i < nt; i++) {
            float ee = __expf(pm[(b << 4) + i] - M);
            e[i] = ee;
            L += ee * pl[(b << 4) + i];
        }
        Linv = 1.f / L;
    }
    __syncthreads();
    for (int d = tid; d < Dd; d += 256) {
        float o = 0.f;
        for (int i = 0; i < nt; i++)
            o += e[i] * psum[((size_t)((b << 4) + i)) * Dd + d];
        o *= Linv;
        out[(size_t)b * 1024 + 512 + d] = o;                 // cat, second half
        out[(size_t)Bb * 1024 + (size_t)b * 512 + d] = o;    // attention_output
        out[(size_t)b * 1024 + d] = col[(size_t)b * Dd + d]; // cat, first half
    }
}

extern "C" void kernel_launch(void* const* d_in, const int* in_sizes, int n_in,
                              void* d_out, int out_size, void* d_ws, size_t ws_size,
                              hipStream_t stream) {
    const float* col  = (const float*)d_in[0];   // [128,512]
    const float* X    = (const float*)d_in[1];   // [128,2048,512]
    const int*   mask = (const int*)d_in[2];     // [128,2048]
    const float* W    = (const float*)d_in[3];   // [512,512]
    float* out = (float*)d_out;

    char* ws = (char*)d_ws;
    _Float16* W16   = (_Float16*)ws;                     // 0    .. 512K
    float*    colt  = (float*)(ws + (512 << 10));        // 512K .. 768K
    float*    psum  = (float*)(ws + (1024 << 10));       // 1M .. 5M (128*16*512 f32)
    float*    pm    = (float*)(ws + (5120 << 10));       // +8K
    float*    pl    = (float*)(ws + (5128 << 10));       // +8K
    int*      cidx  = (int*)(ws + (5136 << 10));         // +1MB
    int*      cnt   = (int*)(ws + (6160 << 10));         // +512B
    int*      tlist = (int*)(ws + (6161 << 10));         // +16KB
    int*      ntile = (int*)(ws + (6180 << 10));         // +4B

    hipMemsetAsync(ntile, 0, 4, stream);
    hipLaunchKernelGGL(prep_kernel, dim3(1408), dim3(256), 0, stream,
                       W, W16, mask, cidx, cnt, tlist, ntile, col, colt);
    hipLaunchKernelGGL(scores_kernel, dim3(NG), dim3(1024), 0, stream,
                       X, W16, colt, cidx, cnt, tlist, ntile, pm, pl, psum);
    hipLaunchKernelGGL(final_kernel, dim3(Bb), dim3(256), 0, stream,
                       pm, pl, psum, cnt, col, out);
}

// Round 17
// 177.550 us; speedup vs baseline: 1.7746x; 1.0359x over previous
//
#include <hip/hip_runtime.h>
#include <cstdint>
#include <cstddef>

#define Bb 128
#define Tt 2048
#define Dd 512
#define Hh 512
#define Mtot (Bb*Tt)
#define NG 1152   // scores grid; grid-stride covers pathological masks

typedef __attribute__((ext_vector_type(8))) _Float16 h8;
typedef __attribute__((ext_vector_type(4))) _Float16 h4v;
typedef __attribute__((ext_vector_type(4))) float f4;

// Direct global->LDS DMA, 16B per lane. LDS dest is WAVE-UNIFORM base; HW
// writes lane l at base + l*16. Global src is per-lane (pre-swizzled).
#define GLOAD_LDS16(gsrc, ldst) \
    __builtin_amdgcn_global_load_lds((const __attribute__((address_space(1))) void*)(gsrc), \
                                     (__attribute__((address_space(3))) void*)(ldst), 16, 0, 0)

__device__ __forceinline__ h4v cvt4s(const float4 a) {
    h4v h;
    h[0] = (_Float16)a.x; h[1] = (_Float16)a.y;
    h[2] = (_Float16)a.z; h[3] = (_Float16)a.w;
    return h;
}

// ---------------- kernel 1: fused prep (unchanged) ----------------
__global__ __launch_bounds__(256) void prep_kernel(
    const float* __restrict__ W, _Float16* __restrict__ W16,
    const int* __restrict__ mask, int* __restrict__ cidx, int* __restrict__ cnt,
    int* __restrict__ tlist, int* __restrict__ ntiles,
    const float* __restrict__ col, float* __restrict__ colt)
{
    const int blk = blockIdx.x, tid = threadIdx.x;
    if (blk < 1024) {                       // ---- W16 cast ----
        int i = blk * 256 + tid;
        W16[i] = (_Float16)W[i];
        return;
    }
    if (blk < 1152) {                       // ---- compaction (b = blk-1024) ----
        __shared__ int wsum[4];
        int b = blk - 1024;
        const int* mrow = mask + (size_t)b * Tt;
        int mv[8], c = 0;
#pragma unroll
        for (int i = 0; i < 8; i++) {
            mv[i] = mrow[tid * 8 + i];
            c += mv[i];
        }
        int lane = tid & 63, wv = tid >> 6;
        int inc = c;
#pragma unroll
        for (int off = 1; off < 64; off <<= 1) {
            int n = __shfl_up(inc, off);
            if (lane >= off) inc += n;
        }
        if (lane == 63) wsum[wv] = inc;
        __syncthreads();
        int wbase = 0;
        for (int w = 0; w < wv; w++) wbase += wsum[w];
        int pos = wbase + inc - c;          // exclusive prefix
        int* crow = cidx + (size_t)b * Tt;
#pragma unroll
        for (int i = 0; i < 8; i++)
            if (mv[i]) crow[pos++] = tid * 8 + i;
        if (tid == 255) {
            int total = wbase + inc;
            cnt[b] = total;
            int nt = (total + 127) >> 7;    // tiles of 128 rows
            int base = atomicAdd(ntiles, nt);
            for (int i = 0; i < nt; i++) tlist[base + i] = (b << 8) | i;
        }
        return;
    }
    {                                        // ---- col_proj ----
        __shared__ float c[Dd];
        int idx = blk - 1152;
        int b = idx >> 1;
        int h = (idx & 1) * 256 + tid;
        c[tid] = col[b * Dd + tid];
        c[tid + 256] = col[b * Dd + 256 + tid];
        __syncthreads();
        const f4* w4 = (const f4*)(W + (size_t)h * Dd);
        float acc = 0.f;
#pragma unroll 8
        for (int k = 0; k < Dd / 4; k++) {
            f4 w = w4[k];
            acc += w.x * c[4 * k] + w.y * c[4 * k + 1] + w.z * c[4 * k + 2] + w.w * c[4 * k + 3];
        }
        colt[b * Hh + h] = fmaxf(acc, 0.f);
    }
}

// ---------------- kernel 2: scores GEMM + FLASH partial (fused) -------------
// R16 structure. NEW: s_setprio(1) around the MFMA cluster (T5) — with 2
// independently-phased blocks per CU (confirmed by R12's LDS regression),
// the MFMA-phase block can preempt the staging-phase block (m191 regime).
__global__ __launch_bounds__(1024, 4) void scores_kernel(
    const float* __restrict__ X,        // [B*T][512]
    const _Float16* __restrict__ W16,   // [512][512]
    const float* __restrict__ colt,     // [128][512]
    const int* __restrict__ cidx,       // [B][T]
    const int* __restrict__ cnt,        // [B]
    const int* __restrict__ tlist,      // work list: (b<<8)|tile
    const int* __restrict__ ntiles,     // [1]
    float* __restrict__ pm,             // [128*16] tile max
    float* __restrict__ pl,             // [128*16] tile exp-sum
    float* __restrict__ psum)           // [128*16][512] weighted X partials
{
    const int tid = threadIdx.x;
    const int total = ntiles[0];

    __shared__ __align__(16) char lds[81920];
    float (*sred)[128] = (float(*)[128])(lds + 65536);
    float* srow  = (float*)(lds + 67584);   // [128]
    float* wrow  = (float*)(lds + 68096);   // [128]
    int*   sidx2 = (int*)  (lds + 68608);   // [128]
    float* scr   = (float*)(lds + 69120);   // [4]
    float* red   = (float*)lds;             // [8][512] aliases bufW0

    const int wave = tid >> 6;
    const int lane = tid & 63;
    const int wm = wave >> 2;   // 0..3 : M quarter
    const int wn = wave & 3;    // 0..3 : N strip
    const int l16 = lane & 15;
    const int khi = lane >> 4;  // 0..3

    int wsrcoff[2];
#pragma unroll
    for (int j = 0; j < 2; j++) {
        int r = (j * 16 + wave) * 16 + (lane >> 2);
        int c = (lane & 3) ^ ((r >> 1) & 3);
        wsrcoff[j] = r * Dd + c * 8;
    }
    const int wldsoff = wave * 1024;   // + j*16384 per chunk-call

    const int xrow = tid >> 3, xf4 = tid & 7;
    const int xoff = xrow * 64 + (((xf4 >> 1) ^ ((xrow >> 1) & 3)) << 4) + (xf4 & 1) * 8;

    for (int idx = blockIdx.x; idx < total; idx += NG) {
        const int ent = tlist[idx];
        const int b = ent >> 8;
        const int tile = ent & 255;
        const int count = cnt[b];
        const int r0 = tile * 128;

        const int* crow = cidx + (size_t)b * Tt;
        int rl = r0 + xrow; if (rl >= count) rl = count - 1;  // clamp (dup, never stored)
        const float* xsrc = X + ((size_t)b * Tt + crow[rl]) * Dd + xf4 * 4;

        f4 acc[2][8];
#pragma unroll
        for (int i = 0; i < 2; i++)
#pragma unroll
            for (int j = 0; j < 8; j++) {
                f4 z = {0.f, 0.f, 0.f, 0.f};
                acc[i][j] = z;
            }

        // ---- prologue: W_0 DMA -> bufW0; X_0 -> LDS; X_1 -> regs ----
        __builtin_amdgcn_sched_barrier(0);
#pragma unroll
        for (int j = 0; j < 2; j++)
            GLOAD_LDS16(W16 + wsrcoff[j], lds + wldsoff + j * 16384);
        __builtin_amdgcn_sched_barrier(0);
        float4 x0 = *(const float4*)(xsrc);
        float4 xu = *(const float4*)(xsrc + 32);
        __builtin_amdgcn_sched_barrier(0);
        {
            h4v hv = cvt4s(x0);        // waits x0 -> drains W_0 DMAs too (in-order)
            *(h4v*)(lds + 65536 + xoff) = hv;
        }
        asm volatile("s_waitcnt vmcnt(1) lgkmcnt(0)" ::: "memory");
        __builtin_amdgcn_sched_barrier(0);
        __builtin_amdgcn_s_barrier();
        __builtin_amdgcn_sched_barrier(0);

#pragma unroll 2
        for (int t = 0; t < 16; ++t) {
            const int cur = t & 1;
            const int kW = (t < 15 ? t + 1 : 15) * 32;  // halfs (tail: dead re-stage)
            const int kX = (t < 14 ? t + 2 : 15) * 32;  // floats (tail: dead load)

            // ---- issue W_{t+1} DMA into bufW[cur^1], then X_{t+2} load ----
            char* bufWn = lds + (cur ^ 1) * 32768;
            __builtin_amdgcn_sched_barrier(0);
#pragma unroll
            for (int j = 0; j < 2; j++)
                GLOAD_LDS16(W16 + wsrcoff[j] + kW, bufWn + wldsoff + j * 16384);
            __builtin_amdgcn_sched_barrier(0);
            float4 xn = *(const float4*)(xsrc + kX);
            __builtin_amdgcn_sched_barrier(0);

            // ---- compute tile t from buf[cur] ----
            const char* bW = lds + cur * 32768;
            const char* bX = lds + 65536 + cur * 8192;
            h8 a[2];
#pragma unroll
            for (int mr = 0; mr < 2; mr++) {
                int row = wm * 32 + mr * 16 + l16;
                a[mr] = *(const h8*)(bX + row * 64 + ((khi ^ ((row >> 1) & 3)) << 4));
            }
            __builtin_amdgcn_s_setprio(1);   // T5: favor MFMA-phase waves
#pragma unroll
            for (int nr = 0; nr < 8; nr++) {
                int row = wn * 128 + nr * 16 + l16;
                h8 bf = *(const h8*)(bW + row * 64 + ((khi ^ ((row >> 1) & 3)) << 4));
                acc[0][nr] = __builtin_amdgcn_mfma_f32_16x16x32_f16(a[0], bf, acc[0][nr], 0, 0, 0);
                acc[1][nr] = __builtin_amdgcn_mfma_f32_16x16x32_f16(a[1], bf, acc[1][nr], 0, 0, 0);
            }
            __builtin_amdgcn_s_setprio(0);

            // ---- write X(t+1) (regs xu) into bufX[cur^1] ----
            {
                h4v hv = cvt4s(xu);    // waits X(t+1) (queue head after W(t+1))
                *(h4v*)(lds + 65536 + (cur ^ 1) * 8192 + xoff) = hv;
            }
            // Queue = [Wa(t+1), Wb(t+1), X(t+2)] -> vmcnt(1) certifies the
            // W-DMAs, keeps the X prefetch in flight.
            asm volatile("s_waitcnt vmcnt(1) lgkmcnt(0)" ::: "memory");
            __builtin_amdgcn_sched_barrier(0);
            __builtin_amdgcn_s_barrier();
            __builtin_amdgcn_sched_barrier(0);
            xu = xn;
        }

        // ---- epilogue 1: relu * colt, reduce over N -> sred ----
        float rs[2][4];
#pragma unroll
        for (int mr = 0; mr < 2; mr++)
#pragma unroll
            for (int r = 0; r < 4; r++) rs[mr][r] = 0.f;
#pragma unroll
        for (int nr = 0; nr < 8; nr++) {
            float cv = colt[b * Hh + wn * 128 + nr * 16 + l16];
#pragma unroll
            for (int mr = 0; mr < 2; mr++)
#pragma unroll
                for (int r = 0; r < 4; r++)
                    rs[mr][r] += fmaxf(acc[mr][nr][r], 0.f) * cv;
        }
#pragma unroll
        for (int mr = 0; mr < 2; mr++)
#pragma unroll
            for (int r = 0; r < 4; r++) {
                float v = rs[mr][r];
                v += __shfl_xor(v, 1);
                v += __shfl_xor(v, 2);
                v += __shfl_xor(v, 4);
                v += __shfl_xor(v, 8);
                rs[mr][r] = v;
            }
        if (l16 == 0) {
#pragma unroll
            for (int mr = 0; mr < 2; mr++)
#pragma unroll
                for (int r = 0; r < 4; r++)
                    sred[wn][wm * 32 + mr * 16 + khi * 4 + r] = rs[mr][r];
        }
        __syncthreads();

        // ---- epilogue 2: flash partial (m_i, w, l_i) ----
        if (tid < 128) {
            int r = r0 + tid;
            bool valid = r < count;
            float s = sred[0][tid] + sred[1][tid] + sred[2][tid] + sred[3][tid];
            s = valid ? s : -1e30f;
            srow[tid] = s;
            sidx2[tid] = crow[valid ? r : (count - 1)];
            float mv = s;
#pragma unroll
            for (int off = 1; off < 64; off <<= 1) mv = fmaxf(mv, __shfl_xor(mv, off));
            if (lane == 0) scr[wave] = mv;   // wave in {0,1} here
        }
        __syncthreads();
        const float mloc = fmaxf(scr[0], scr[1]);
        if (tid < 128) {
            float s = srow[tid];
            float e = (s > -1e29f) ? __expf(s - mloc) : 0.f;
            wrow[tid] = e;
#pragma unroll
            for (int off = 1; off < 64; off <<= 1) e += __shfl_xor(e, off);
            if (lane == 0) scr[2 + wave] = e;
        }
        __syncthreads();
        if (tid == 0) {
            pm[(b << 4) + tile] = mloc;
            pl[(b << 4) + tile] = scr[2] + scr[3];
        }

        // ---- epilogue 3: weighted X repass -> psum ----
        {
            const int rgrp = tid >> 7;      // 0..7 (wave-uniform)
            const int cg = tid & 127;       // float4 col slice
            float ax = 0.f, ay = 0.f, az = 0.f, aw = 0.f;
            const float* xb2 = X + (size_t)b * Tt * Dd + cg * 4;
#pragma unroll 4
            for (int r = rgrp; r < 128; r += 8) {
                const float4 xv = *(const float4*)(xb2 + (size_t)sidx2[r] * Dd);
                float wv = wrow[r];         // 0 for padded rows
                ax += wv * xv.x; ay += wv * xv.y; az += wv * xv.z; aw += wv * xv.w;
            }
            float4 st = {ax, ay, az, aw};
            *(float4*)(red + rgrp * 512 + cg * 4) = st;
        }
        __syncthreads();
        if (tid < 128) {
            int cg = tid;
            float ax = 0.f, ay = 0.f, az = 0.f, aw = 0.f;
#pragma unroll
            for (int g = 0; g < 8; g++) {
                const float4 v = *(const float4*)(red + g * 512 + cg * 4);
                ax += v.x; ay += v.y; az += v.z; aw += v.w;
            }
            float4 st = {ax, ay, az, aw};
            *(float4*)(psum + ((size_t)((b << 4) + tile)) * Dd + cg * 4) = st;
        }
        __syncthreads();   // protect red/scratch/bufW0 before next iteration
    }
}

// ---------------- kernel 3: final combine per b (vectorized) -----------------
__global__ __launch_bounds__(256) void final_kernel(
    const float* __restrict__ pm, const float* __restrict__ pl,
    const float* __restrict__ psum, const int* __restrict__ cnt,
    const float* __restrict__ col, float* __restrict__ out)
{
    __shared__ float e[16];
    __shared__ float Linv;
    int b = blockIdx.x, tid = threadIdx.x;
    int nt = (cnt[b] + 127) >> 7;
    if (tid == 0) {
        float M = -1e30f;
        for (int i = 0; i < nt; i++) M = fmaxf(M, pm[(b << 4) + i]);
        float L = 0.f;
        for (int i = 0; i < nt; i++) {
            float ee = __expf(pm[(b << 4) + i] - M);
            e[i] = ee;
            L += ee * pl[(b << 4) + i];
        }
        Linv = 1.f / L;
    }
    __syncthreads();
    if (tid < 128) {
        int d4 = tid;   // float4 index, 128 x 4 = 512
        float ax = 0.f, ay = 0.f, az = 0.f, aw = 0.f;
        for (int i = 0; i < nt; i++) {
            const float4 v = *(const float4*)(psum + ((size_t)((b << 4) + i)) * Dd + d4 * 4);
            float ee = e[i];
            ax += ee * v.x; ay += ee * v.y; az += ee * v.z; aw += ee * v.w;
        }
        float4 o = {ax * Linv, ay * Linv, az * Linv, aw * Linv};
        *(float4*)(out + (size_t)b * 1024 + 512 + d4 * 4) = o;
        *(float4*)(out + (size_t)Bb * 1024 + (size_t)b * 512 + d4 * 4) = o;
        const float4 cv = *(const float4*)(col + (size_t)b * Dd + d4 * 4);
        *(float4*)(out + (size_t)b * 1024 + d4 * 4) = cv;
    }
}

extern "C" void kernel_launch(void* const* d_in, const int* in_sizes, int n_in,
                              void* d_out, int out_size, void* d_ws, size_t ws_size,
                              hipStream_t stream) {
    const float* col  = (const float*)d_in[0];   // [128,512]
    const float* X    = (const float*)d_in[1];   // [128,2048,512]
    const int*   mask = (const int*)d_in[2];     // [128,2048]
    const float* W    = (const float*)d_in[3];   // [512,512]
    float* out = (float*)d_out;

    char* ws = (char*)d_ws;
    _Float16* W16   = (_Float16*)ws;                     // 0    .. 512K
    float*    colt  = (float*)(ws + (512 << 10));        // 512K .. 768K
    float*    psum  = (float*)(ws + (1024 << 10));       // 1M .. 5M (128*16*512 f32)
    float*    pm    = (float*)(ws + (5120 << 10));       // +8K
    float*    pl    = (float*)(ws + (5128 << 10));       // +8K
    int*      cidx  = (int*)(ws + (5136 << 10));         // +1MB
    int*      cnt   = (int*)(ws + (6160 << 10));         // +512B
    int*      tlist = (int*)(ws + (6161 << 10));         // +16KB
    int*      ntile = (int*)(ws + (6180 << 10));         // +4B

    hipMemsetAsync(ntile, 0, 4, stream);
    hipLaunchKernelGGL(prep_kernel, dim3(1408), dim3(256), 0, stream,
                       W, W16, mask, cidx, cnt, tlist, ntile, col, colt);
    hipLaunchKernelGGL(scores_kernel, dim3(NG), dim3(1024), 0, stream,
                       X, W16, colt, cidx, cnt, tlist, ntile, pm, pl, psum);
    hipLaunchKernelGGL(final_kernel, dim3(Bb), dim3(256), 0, stream,
                       pm, pl, psum, cnt, col, out);
}